// Round 11
// baseline (99.548 us; speedup 1.0000x reference)
//
#include <hip/hip_runtime.h>
#include <stdint.h>

#define WIN 8
#define DEG 16
#define ORDER 500
#define STEPS_C 50
#define T1 51          // STEPS+1
#define FRD 15         // feature rows = 2*WIN-1
#define NI 8           // adj_bits words per node
#define WPB 125        // walkers per block
#define BLOCK 256
#define NSTR 52        // nodes/eidx row stride (elements)

// Fused kernel v2: serial walk records ONLY the node/edge sequence;
// id/adj window features are pure post-hoc functions of that sequence
// (id[k]@τ = nodes[τ-8+k]==nodes[τ]; adj[k]@τ = bit(g_bits[nodes[τ-8+k]],
// nodes[τ]); valid ⇔ τ-8+k >= 0) and are computed in the parallel,
// HBM-bound expand phase instead of the serial chain.
//
// LDS (51520 B -> 3 blocks/CU), all live for whole kernel:
//   [0,16000)     g_adj  u16[500][16]  (local ids)
//   [16000,32000) g_bits int[500][8]
//   [32000,45000) nodes_l u16[125][52]
//   [45000,51500) eidx_l  u8[125][52]
__global__ __launch_bounds__(256)
void fused_kernel(const int* __restrict__ adj_nodes,
                  const int* __restrict__ adj_bits,
                  const int* __restrict__ choices,
                  float* __restrict__ out, int N)
{
    __shared__ unsigned long long smem[6440];   // 51520 B
    unsigned short* g_adj   = (unsigned short*)smem;
    int*            g_bits  = (int*)((char*)smem + 16000);
    unsigned short* nodes_l = (unsigned short*)((char*)smem + 32000);
    unsigned char*  eidx_l  = (unsigned char*)((char*)smem + 45000);

    const int tid = threadIdx.x;

    // bijective XCD swizzle (nwg=400: q8=50) -> same-graph blocks share an XCD
    const int nwg = gridDim.x;
    const int q8  = nwg >> 3;
    const int vb  = ((nwg & 7) == 0) ? ((blockIdx.x & 7) * q8 + (blockIdx.x >> 3))
                                     : blockIdx.x;

    const int graph  = vb >> 2;              // 4 blocks per graph
    const int lb     = vb & 3;
    const int gbase  = graph * ORDER;
    const int lstart = lb * WPB + tid;       // local walker id in graph
    const bool act   = (tid < WPB);
    const int wi     = gbase + lstart;
    const int wild   = act ? wi : gbase;     // safe load index
    const int wbase  = vb * WPB;             // first global walker of block

    // ---- stage graph tables into LDS (coalesced) ----
    {
        const int4* src = (const int4*)(adj_nodes + (size_t)gbase * DEG);
        unsigned* dst = (unsigned*)g_adj;
        for (int c = tid; c < ORDER * DEG / 4; c += BLOCK) {
            const int4 v = src[c];
            dst[2 * c + 0] = (unsigned)(v.x - gbase) | ((unsigned)(v.y - gbase) << 16);
            dst[2 * c + 1] = (unsigned)(v.z - gbase) | ((unsigned)(v.w - gbase) << 16);
        }
        int4* db = (int4*)g_bits;
        const int4* sb = (const int4*)(adj_bits + (size_t)gbase * NI);
        for (int c = tid; c < ORDER * NI / 4; c += BLOCK) db[c] = sb[c];
    }
    __syncthreads();

    // ---- walk phase: minimal serial chain (nodes + edge indices only) ----
    if (act) {
        int prev = -1;            // w[6]
        int cur  = lstart;        // w[7]

        nodes_l[tid * NSTR] = (unsigned short)lstart;

        // depth-8 rolling register prefetch of choices (coalesced, named regs)
        int c0 = choices[wild];
        int c1 = choices[(size_t)1 * N + wild];
        int c2 = choices[(size_t)2 * N + wild];
        int c3 = choices[(size_t)3 * N + wild];
        int c4 = choices[(size_t)4 * N + wild];
        int c5 = choices[(size_t)5 * N + wild];
        int c6 = choices[(size_t)6 * N + wild];
        int c7 = choices[(size_t)7 * N + wild];

        for (int t = 0; t < STEPS_C; t++) {
            const int ch = c0;
            c0 = c1; c1 = c2; c2 = c3; c3 = c4; c4 = c5; c5 = c6; c6 = c7;
            c7 = (t + 8 < STEPS_C) ? choices[(size_t)(t + 8) * N + wild] : 0;

            // deg==16 pow2: floored mod == AND (valid for negatives)
            const int e = ch & (DEG - 1);
            int r15 = ch % (DEG - 1); if (r15 < 0) r15 += (DEG - 1);
            const int e2 = (e + 1 + r15) & (DEG - 1);

            const int n1 = g_adj[cur * DEG + e];
            const int n2 = g_adj[cur * DEG + e2];

            const bool bt = (t >= 1) && (n1 == prev);
            const int nn = bt ? n2 : n1;        // local id
            const int ee = bt ? e2 : e;         // edge index [0,16)

            nodes_l[tid * NSTR + t + 1] = (unsigned short)nn;
            eidx_l[tid * NSTR + t]      = (unsigned char)ee;

            prev = cur;
            cur  = nn;
        }
    }
    __syncthreads();

    // ---- expand phase: all 256 threads, aligned float4 streams ----

    // out0: walk_nodes [wl][51] = gbase + nodes_l[wl][t]   (125*51 = 6375 floats)
    {
        float* dst = out + (size_t)wbase * T1;
        const int count = WPB * T1;
        const int head = (4 - (int)((((uintptr_t)dst) >> 2) & 3)) & 3;
        for (int i = tid; i < head; i += BLOCK) {
            const int wl = i / T1, t = i - wl * T1;
            dst[i] = (float)(gbase + (int)nodes_l[wl * NSTR + t]);
        }
        const int n4 = (count - head) >> 2;
        for (int c = tid; c < n4; c += BLOCK) {
            const int f0 = head + (c << 2);
            int wl = f0 / T1, t = f0 - wl * T1;
            float vv[4];
#pragma unroll
            for (int u = 0; u < 4; u++) {
                vv[u] = (float)(gbase + (int)nodes_l[wl * NSTR + t]);
                t++; if (t == T1) { t = 0; wl++; }
            }
            float4 v; v.x = vv[0]; v.y = vv[1]; v.z = vv[2]; v.w = vv[3];
            *reinterpret_cast<float4*>(dst + f0) = v;
        }
        const int done = head + (n4 << 2);
        for (int i = done + tid; i < count; i += BLOCK) {
            const int wl = i / T1, t = i - wl * T1;
            dst[i] = (float)(gbase + (int)nodes_l[wl * NSTR + t]);
        }
    }

    // out1: walk_edges [wl][50] = ((gbase+cur)<<4)+eidx   (125*50 = 6250 floats)
    {
        float* dst = out + (size_t)N * T1 + (size_t)wbase * STEPS_C;
        const int count = WPB * STEPS_C;
        const int head = (4 - (int)((((uintptr_t)dst) >> 2) & 3)) & 3;
        for (int i = tid; i < head; i += BLOCK) {
            const int wl = i / STEPS_C, t = i - wl * STEPS_C;
            dst[i] = (float)((((gbase + (int)nodes_l[wl * NSTR + t])) << 4)
                             + (int)eidx_l[wl * NSTR + t]);
        }
        const int n4 = (count - head) >> 2;
        for (int c = tid; c < n4; c += BLOCK) {
            const int f0 = head + (c << 2);
            int wl = f0 / STEPS_C, t = f0 - wl * STEPS_C;
            float vv[4];
#pragma unroll
            for (int u = 0; u < 4; u++) {
                vv[u] = (float)((((gbase + (int)nodes_l[wl * NSTR + t])) << 4)
                                + (int)eidx_l[wl * NSTR + t]);   // < 2^24, exact
                t++; if (t == STEPS_C) { t = 0; wl++; }
            }
            float4 v; v.x = vv[0]; v.y = vv[1]; v.z = vv[2]; v.w = vv[3];
            *reinterpret_cast<float4*>(dst + f0) = v;
        }
        const int done = head + (n4 << 2);
        for (int i = done + tid; i < count; i += BLOCK) {
            const int wl = i / STEPS_C, t = i - wl * STEPS_C;
            dst[i] = (float)((((gbase + (int)nodes_l[wl * NSTR + t])) << 4)
                             + (int)eidx_l[wl * NSTR + t]);
        }
    }

    // out2: walk_x [wl][j<15][t<51]  (125*765 = 95625 floats)
    //   j<8 : id row  = (t-8+j >= 0) && nodes[t-8+j]==nodes[t]
    //   j>=8: adj row = (t-16+j >= 0) && bit(g_bits[nodes[t-16+j]], nodes[t])
    {
        float* dst = out + (size_t)N * (T1 + STEPS_C) + (size_t)wbase * (FRD * T1);
        const int count = WPB * FRD * T1;
        const int head = (4 - (int)((((uintptr_t)dst) >> 2) & 3)) & 3;

        auto feat = [&](int wl, int j, int t) -> float {
            const int base = wl * NSTR;
            if (j < 8) {
                const int src = t - 8 + j;
                return (src >= 0 && nodes_l[base + t] == nodes_l[base + src])
                       ? 1.0f : 0.0f;
            } else {
                const int src = t - 16 + j;     // t-8+(j-8)
                if (src < 0) return 0.0f;
                const int a = (int)nodes_l[base + src];
                const int b = (int)nodes_l[base + t];
                const unsigned q  = (unsigned)b / 63u;
                const unsigned rr = (unsigned)b - q * 63u;
                const unsigned s  = rr > 31u ? 31u : rr;   // int32 saturating shift
                return ((g_bits[a * NI + q] >> s) & 1) ? 1.0f : 0.0f;
            }
        };

        for (int i = tid; i < head; i += BLOCK) {
            const int wl = i / (FRD * T1), rem = i - wl * (FRD * T1);
            dst[i] = feat(wl, rem / T1, rem % T1);
        }
        const int n4 = (count - head) >> 2;
        for (int c = tid; c < n4; c += BLOCK) {
            const int f0 = head + (c << 2);
            int wl = f0 / (FRD * T1), rem = f0 - wl * (FRD * T1);
            int j = rem / T1, t = rem - j * T1;
            float vv[4];
#pragma unroll
            for (int u = 0; u < 4; u++) {
                vv[u] = feat(wl, j, t);
                t++;
                if (t == T1) { t = 0; j++; if (j == FRD) { j = 0; wl++; } }
            }
            float4 v; v.x = vv[0]; v.y = vv[1]; v.z = vv[2]; v.w = vv[3];
            *reinterpret_cast<float4*>(dst + f0) = v;
        }
        const int done = head + (n4 << 2);
        for (int i = done + tid; i < count; i += BLOCK) {
            const int wl = i / (FRD * T1), rem = i - wl * (FRD * T1);
            dst[i] = feat(wl, rem / T1, rem % T1);
        }
    }
}

extern "C" void kernel_launch(void* const* d_in, const int* in_sizes, int n_in,
                              void* d_out, int out_size, void* d_ws, size_t ws_size,
                              hipStream_t stream) {
    const int N = in_sizes[3];               // 50000
    const int num_graphs = N / ORDER;        // 100
    const int grid = num_graphs * 4;         // 400 blocks, 125 walkers each

    fused_kernel<<<grid, BLOCK, 0, stream>>>(
        (const int*)d_in[0], (const int*)d_in[4], (const int*)d_in[5],
        (float*)d_out, N);
}

// Round 12
// 73.746 us; speedup vs baseline: 1.3499x; 1.3499x over previous
//
#include <hip/hip_runtime.h>
#include <stdint.h>

#define WIN 8
#define DEG 16
#define ORDER 500
#define STEPS_C 50
#define T1 51          // STEPS+1
#define FRD 15         // feature rows = 2*WIN-1
#define NI 8           // adj_bits words per node
#define WPB 63         // walkers per block (last block of graph: 59)
#define BPG 8          // blocks per graph
#define BLOCK 256
#define MSTR 17        // mask row stride in u64 (odd -> conflict-free)
#define NSTR 52        // nodes/eidx row stride (elements)

// Fused kernel (r10 structure, r12 geometry): each block walks <=63 walkers
// (walker-per-thread, masks accumulated in registers during the walk) and
// then expands its own outputs. 800 blocks -> ~3 resident/CU -> 12
// store-waves/CU during the HBM-bound expand phase.
//
// LDS time-union (41832 B -> 3 blocks/CU):
//   walk phase:   [0,16000) g_adj u16 | [16000,32000) g_bits int
//   expand phase: [0,8568)  mask_l u64[63][17]   (tables dead by then)
//   both:         [32000,38552) nodes_l u16[63][52]
//                 [38552,41828) eidx_l  u8[63][52]
__global__ __launch_bounds__(256)
void fused_kernel(const int* __restrict__ adj_nodes,
                  const int* __restrict__ adj_bits,
                  const int* __restrict__ choices,
                  float* __restrict__ out, int N)
{
    __shared__ unsigned long long smem[5229];   // 41832 B
    unsigned short* g_adj   = (unsigned short*)smem;
    int*            g_bits  = (int*)((char*)smem + 16000);
    unsigned long long* mask_l = smem;          // overlays tables after walk
    unsigned short* nodes_l = (unsigned short*)((char*)smem + 32000);
    unsigned char*  eidx_l  = (unsigned char*)((char*)smem + 38552);

    const int tid = threadIdx.x;

    // bijective XCD swizzle (nwg=800: q8=100) -> same-graph blocks share an XCD
    const int nwg = gridDim.x;
    const int q8  = nwg >> 3;
    const int vb  = ((nwg & 7) == 0) ? ((blockIdx.x & 7) * q8 + (blockIdx.x >> 3))
                                     : blockIdx.x;

    const int graph  = vb >> 3;              // BPG=8 blocks per graph
    const int lb     = vb & 7;
    const int gbase  = graph * ORDER;
    const int lstart = lb * WPB + tid;       // local walker id in graph
    const bool act   = (tid < WPB) && (lstart < ORDER);
    const int wi     = gbase + lstart;
    const int wild   = act ? wi : gbase;     // safe load index
    const int wbase  = gbase + lb * WPB;     // first global walker of block
    int nvalid = ORDER - lb * WPB;           // 63, or 59 in last block
    if (nvalid > WPB) nvalid = WPB;

    // ---- stage graph tables into LDS (coalesced) ----
    {
        const int4* src = (const int4*)(adj_nodes + (size_t)gbase * DEG);
        unsigned* dst = (unsigned*)g_adj;
        for (int c = tid; c < ORDER * DEG / 4; c += BLOCK) {
            const int4 v = src[c];
            dst[2 * c + 0] = (unsigned)(v.x - gbase) | ((unsigned)(v.y - gbase) << 16);
            dst[2 * c + 1] = (unsigned)(v.z - gbase) | ((unsigned)(v.w - gbase) << 16);
        }
        int4* db = (int4*)g_bits;
        const int4* sb = (const int4*)(adj_bits + (size_t)gbase * NI);
        for (int c = tid; c < ORDER * NI / 4; c += BLOCK) db[c] = sb[c];
    }
    __syncthreads();

    // ---- walk phase (walker-per-thread; masks in registers; r10-verified) ----
    unsigned long long idm[WIN];
    unsigned long long adm[WIN - 1];
#pragma unroll
    for (int k = 0; k < WIN; k++) idm[k] = 0ull;
#pragma unroll
    for (int k = 0; k < WIN - 1; k++) adm[k] = 0ull;

    if (act) {
        int w[WIN];
#pragma unroll
        for (int k = 0; k < WIN; k++) w[k] = 0;
        w[7] = lstart;

        nodes_l[tid * NSTR] = (unsigned short)lstart;   // row t=0 (local id)

        // depth-8 rolling register prefetch of choices (coalesced, named regs)
        int c0 = choices[wild];
        int c1 = choices[(size_t)1 * N + wild];
        int c2 = choices[(size_t)2 * N + wild];
        int c3 = choices[(size_t)3 * N + wild];
        int c4 = choices[(size_t)4 * N + wild];
        int c5 = choices[(size_t)5 * N + wild];
        int c6 = choices[(size_t)6 * N + wild];
        int c7 = choices[(size_t)7 * N + wild];

        for (int t = 0; t < STEPS_C; t++) {
            const int ch = c0;
            c0 = c1; c1 = c2; c2 = c3; c3 = c4; c4 = c5; c5 = c6; c6 = c7;
            c7 = (t + 8 < STEPS_C) ? choices[(size_t)(t + 8) * N + wild] : 0;

            // deg==16 pow2: floored mod == AND (valid for negatives)
            const int e = ch & (DEG - 1);
            int r15 = ch % (DEG - 1); if (r15 < 0) r15 += (DEG - 1);
            const int e2 = (e + 1 + r15) & (DEG - 1);

            const int cur = w[7];
            const int n1 = g_adj[cur * DEG + e];
            const int n2 = g_adj[cur * DEG + e2];

            const bool bt = (t >= 1) && (n1 == w[6]);
            const int nn = bt ? n2 : n1;        // local id
            const int ee = bt ? e2 : e;         // edge index [0,16)

            // cid == local id directly (node_id closed form)
            const unsigned q  = (unsigned)nn / 63u;
            const unsigned rr = (unsigned)nn - q * 63u;
            const unsigned s  = rr > 31u ? 31u : rr;    // int32 saturating shift
            const unsigned long long bitpos = 1ull << (t + 1);

#pragma unroll
            for (int k = 0; k < WIN; k++) {
                const bool vk = (k + t) >= (WIN - 1);
                if (vk && (w[k] == nn)) idm[k] |= bitpos;
            }
#pragma unroll
            for (int k = 0; k < WIN - 1; k++) {
                const bool vk = (k + t) >= (WIN - 1);
                const int word = g_bits[w[k] * NI + q];
                if (vk && ((word >> s) & 1)) adm[k] |= bitpos;
            }

#pragma unroll
            for (int k = 0; k < WIN - 1; k++) w[k] = w[k + 1];
            w[7] = nn;

            nodes_l[tid * NSTR + t + 1] = (unsigned short)nn;
            eidx_l[tid * NSTR + t]      = (unsigned char)ee;
        }
    }

    // tables are dead from here; barrier, then overlay masks into region A
    __syncthreads();
    if (act) {
#pragma unroll
        for (int k = 0; k < WIN; k++)      mask_l[tid * MSTR + k]     = idm[k];
#pragma unroll
        for (int k = 0; k < WIN - 1; k++)  mask_l[tid * MSTR + 8 + k] = adm[k];
    }
    __syncthreads();

    // ---- expand phase: all 256 threads, aligned float4 streams ----

    // out0: walk_nodes [wl][51] = gbase + nodes_l[wl][t]
    {
        float* dst = out + (size_t)wbase * T1;
        const int count = nvalid * T1;
        const int head = (4 - (int)((((uintptr_t)dst) >> 2) & 3)) & 3;
        for (int i = tid; i < head; i += BLOCK) {
            const int wl = i / T1, t = i - wl * T1;
            dst[i] = (float)(gbase + (int)nodes_l[wl * NSTR + t]);
        }
        const int n4 = (count - head) >> 2;
        for (int c = tid; c < n4; c += BLOCK) {
            const int f0 = head + (c << 2);
            int wl = f0 / T1, t = f0 - wl * T1;
            float vv[4];
#pragma unroll
            for (int u = 0; u < 4; u++) {
                vv[u] = (float)(gbase + (int)nodes_l[wl * NSTR + t]);
                t++; if (t == T1) { t = 0; wl++; }
            }
            float4 v; v.x = vv[0]; v.y = vv[1]; v.z = vv[2]; v.w = vv[3];
            *reinterpret_cast<float4*>(dst + f0) = v;
        }
        const int done = head + (n4 << 2);
        for (int i = done + tid; i < count; i += BLOCK) {
            const int wl = i / T1, t = i - wl * T1;
            dst[i] = (float)(gbase + (int)nodes_l[wl * NSTR + t]);
        }
    }

    // out1: walk_edges [wl][50] = ((gbase+cur)<<4)+eidx   (< 2^24, exact)
    {
        float* dst = out + (size_t)N * T1 + (size_t)wbase * STEPS_C;
        const int count = nvalid * STEPS_C;
        const int head = (4 - (int)((((uintptr_t)dst) >> 2) & 3)) & 3;
        for (int i = tid; i < head; i += BLOCK) {
            const int wl = i / STEPS_C, t = i - wl * STEPS_C;
            dst[i] = (float)((((gbase + (int)nodes_l[wl * NSTR + t])) << 4)
                             + (int)eidx_l[wl * NSTR + t]);
        }
        const int n4 = (count - head) >> 2;
        for (int c = tid; c < n4; c += BLOCK) {
            const int f0 = head + (c << 2);
            int wl = f0 / STEPS_C, t = f0 - wl * STEPS_C;
            float vv[4];
#pragma unroll
            for (int u = 0; u < 4; u++) {
                vv[u] = (float)((((gbase + (int)nodes_l[wl * NSTR + t])) << 4)
                                + (int)eidx_l[wl * NSTR + t]);
                t++; if (t == STEPS_C) { t = 0; wl++; }
            }
            float4 v; v.x = vv[0]; v.y = vv[1]; v.z = vv[2]; v.w = vv[3];
            *reinterpret_cast<float4*>(dst + f0) = v;
        }
        const int done = head + (n4 << 2);
        for (int i = done + tid; i < count; i += BLOCK) {
            const int wl = i / STEPS_C, t = i - wl * STEPS_C;
            dst[i] = (float)((((gbase + (int)nodes_l[wl * NSTR + t])) << 4)
                             + (int)eidx_l[wl * NSTR + t]);
        }
    }

    // out2: walk_x [wl][j<15][t<51] = bit t of mask_l[wl][j]
    {
        float* dst = out + (size_t)N * (T1 + STEPS_C) + (size_t)wbase * (FRD * T1);
        const int count = nvalid * FRD * T1;
        const int head = (4 - (int)((((uintptr_t)dst) >> 2) & 3)) & 3;
        for (int i = tid; i < head; i += BLOCK) {
            const int wl = i / (FRD * T1), rem = i - wl * (FRD * T1);
            const int j = rem / T1, t = rem - j * T1;
            dst[i] = ((mask_l[wl * MSTR + j] >> t) & 1ull) ? 1.0f : 0.0f;
        }
        const int n4 = (count - head) >> 2;
        for (int c = tid; c < n4; c += BLOCK) {
            const int f0 = head + (c << 2);
            int wl = f0 / (FRD * T1), rem = f0 - wl * (FRD * T1);
            int j = rem / T1, t = rem - j * T1;
            float vv[4];
#pragma unroll
            for (int u = 0; u < 4; u++) {
                vv[u] = ((mask_l[wl * MSTR + j] >> t) & 1ull) ? 1.0f : 0.0f;
                t++;
                if (t == T1) { t = 0; j++; if (j == FRD) { j = 0; wl++; } }
            }
            float4 v; v.x = vv[0]; v.y = vv[1]; v.z = vv[2]; v.w = vv[3];
            *reinterpret_cast<float4*>(dst + f0) = v;
        }
        const int done = head + (n4 << 2);
        for (int i = done + tid; i < count; i += BLOCK) {
            const int wl = i / (FRD * T1), rem = i - wl * (FRD * T1);
            const int j = rem / T1, t = rem - j * T1;
            dst[i] = ((mask_l[wl * MSTR + j] >> t) & 1ull) ? 1.0f : 0.0f;
        }
    }
}

extern "C" void kernel_launch(void* const* d_in, const int* in_sizes, int n_in,
                              void* d_out, int out_size, void* d_ws, size_t ws_size,
                              hipStream_t stream) {
    const int N = in_sizes[3];               // 50000
    const int num_graphs = N / ORDER;        // 100
    const int grid = num_graphs * BPG;       // 800 blocks, <=63 walkers each

    fused_kernel<<<grid, BLOCK, 0, stream>>>(
        (const int*)d_in[0], (const int*)d_in[4], (const int*)d_in[5],
        (float*)d_out, N);
}

// Round 13
// 49.683 us; speedup vs baseline: 2.0036x; 1.4843x over previous
//
#include <hip/hip_runtime.h>
#include <stdint.h>

#define WIN 8
#define DEG 16
#define ORDER 500
#define STEPS_C 50
#define T1 51          // STEPS+1
#define FRD 15         // feature rows = 2*WIN-1
#define NI 8           // adj_bits words per node
#define WPB 100        // walkers per block (5*100 = 500 exactly -> all full)
#define BPG 5          // blocks per graph
#define BLOCK 512
#define MSTR 17        // mask row stride in u64 (odd -> conflict-free)
#define NSTR 52        // nodes/eidx row stride (elements)

// Fused kernel (r10 body, r13 geometry): 500 blocks x 512 threads, 100
// walkers/block. One resident generation (LDS 47.6 KB -> 3 blocks/CU cap,
// grid 500 < 768), ~2 blocks/CU balanced, 16 store-waves/CU in expand.
//
// LDS time-union (47600 B):
//   walk phase:   [0,16000) g_adj u16 | [16000,32000) g_bits int
//   expand phase: [0,13600) mask_l u64[100][17]  (tables dead by then)
//   both:         [32000,42400) nodes_l u16[100][52]
//                 [42400,47600) eidx_l  u8[100][52]
//
// WPB=100 alignment: 100*51, 100*50, 100*765 and all block base offsets are
// multiples of 4 floats -> every expand stream is pure float4 (no head/tail).
__global__ __launch_bounds__(512)
void fused_kernel(const int* __restrict__ adj_nodes,
                  const int* __restrict__ adj_bits,
                  const int* __restrict__ choices,
                  float* __restrict__ out, int N)
{
    __shared__ unsigned long long smem[5950];   // 47600 B
    unsigned short* g_adj   = (unsigned short*)smem;
    int*            g_bits  = (int*)((char*)smem + 16000);
    unsigned long long* mask_l = smem;          // overlays tables after walk
    unsigned short* nodes_l = (unsigned short*)((char*)smem + 32000);
    unsigned char*  eidx_l  = (unsigned char*)((char*)smem + 42400);

    const int tid = threadIdx.x;

    // bijective XCD-aware swizzle (m204): nwg=500 -> q=62, r=4
    const int nwg = gridDim.x;
    const int q8  = nwg >> 3, r8 = nwg & 7;
    const int xcd = blockIdx.x & 7, ord = blockIdx.x >> 3;
    const int vb  = (xcd < r8 ? xcd * (q8 + 1) : r8 * (q8 + 1) + (xcd - r8) * q8) + ord;

    const int graph  = vb / BPG;
    const int lb     = vb - graph * BPG;
    const int gbase  = graph * ORDER;
    const int lstart = lb * WPB + tid;       // local walker id in graph (<500 always)
    const bool act   = (tid < WPB);
    const int wi     = gbase + lstart;
    const int wild   = act ? wi : gbase;     // safe load index
    const int wbase  = gbase + lb * WPB;     // first global walker of block

    // ---- stage graph tables into LDS (coalesced) ----
    {
        const int4* src = (const int4*)(adj_nodes + (size_t)gbase * DEG);
        unsigned* dst = (unsigned*)g_adj;
        for (int c = tid; c < ORDER * DEG / 4; c += BLOCK) {
            const int4 v = src[c];
            dst[2 * c + 0] = (unsigned)(v.x - gbase) | ((unsigned)(v.y - gbase) << 16);
            dst[2 * c + 1] = (unsigned)(v.z - gbase) | ((unsigned)(v.w - gbase) << 16);
        }
        int4* db = (int4*)g_bits;
        const int4* sb = (const int4*)(adj_bits + (size_t)gbase * NI);
        for (int c = tid; c < ORDER * NI / 4; c += BLOCK) db[c] = sb[c];
    }
    __syncthreads();

    // ---- walk phase (walker-per-thread; masks in registers; r10-verified) ----
    unsigned long long idm[WIN];
    unsigned long long adm[WIN - 1];
#pragma unroll
    for (int k = 0; k < WIN; k++) idm[k] = 0ull;
#pragma unroll
    for (int k = 0; k < WIN - 1; k++) adm[k] = 0ull;

    if (act) {
        int w[WIN];
#pragma unroll
        for (int k = 0; k < WIN; k++) w[k] = 0;
        w[7] = lstart;

        nodes_l[tid * NSTR] = (unsigned short)lstart;   // row t=0 (local id)

        // depth-8 rolling register prefetch of choices (coalesced, named regs)
        int c0 = choices[wild];
        int c1 = choices[(size_t)1 * N + wild];
        int c2 = choices[(size_t)2 * N + wild];
        int c3 = choices[(size_t)3 * N + wild];
        int c4 = choices[(size_t)4 * N + wild];
        int c5 = choices[(size_t)5 * N + wild];
        int c6 = choices[(size_t)6 * N + wild];
        int c7 = choices[(size_t)7 * N + wild];

        for (int t = 0; t < STEPS_C; t++) {
            const int ch = c0;
            c0 = c1; c1 = c2; c2 = c3; c3 = c4; c4 = c5; c5 = c6; c6 = c7;
            c7 = (t + 8 < STEPS_C) ? choices[(size_t)(t + 8) * N + wild] : 0;

            // deg==16 pow2: floored mod == AND (valid for negatives)
            const int e = ch & (DEG - 1);
            int r15 = ch % (DEG - 1); if (r15 < 0) r15 += (DEG - 1);
            const int e2 = (e + 1 + r15) & (DEG - 1);

            const int cur = w[7];
            const int n1 = g_adj[cur * DEG + e];
            const int n2 = g_adj[cur * DEG + e2];

            const bool bt = (t >= 1) && (n1 == w[6]);
            const int nn = bt ? n2 : n1;        // local id
            const int ee = bt ? e2 : e;         // edge index [0,16)

            // cid == local id directly (node_id closed form)
            const unsigned q  = (unsigned)nn / 63u;
            const unsigned rr = (unsigned)nn - q * 63u;
            const unsigned s  = rr > 31u ? 31u : rr;    // int32 saturating shift
            const unsigned long long bitpos = 1ull << (t + 1);

#pragma unroll
            for (int k = 0; k < WIN; k++) {
                const bool vk = (k + t) >= (WIN - 1);
                if (vk && (w[k] == nn)) idm[k] |= bitpos;
            }
#pragma unroll
            for (int k = 0; k < WIN - 1; k++) {
                const bool vk = (k + t) >= (WIN - 1);
                const int word = g_bits[w[k] * NI + q];
                if (vk && ((word >> s) & 1)) adm[k] |= bitpos;
            }

#pragma unroll
            for (int k = 0; k < WIN - 1; k++) w[k] = w[k + 1];
            w[7] = nn;

            nodes_l[tid * NSTR + t + 1] = (unsigned short)nn;
            eidx_l[tid * NSTR + t]      = (unsigned char)ee;
        }
    }

    // tables are dead from here; barrier, then overlay masks into region A
    __syncthreads();
    if (act) {
#pragma unroll
        for (int k = 0; k < WIN; k++)      mask_l[tid * MSTR + k]     = idm[k];
#pragma unroll
        for (int k = 0; k < WIN - 1; k++)  mask_l[tid * MSTR + 8 + k] = adm[k];
    }
    __syncthreads();

    // ---- expand phase: all 512 threads, pure float4 streams (aligned) ----

    // out0: walk_nodes [wl][51] = gbase + nodes_l[wl][t]   (5100 floats)
    {
        float* dst = out + (size_t)wbase * T1;
        const int n4 = (WPB * T1) >> 2;          // 1275
        for (int c = tid; c < n4; c += BLOCK) {
            const int f0 = c << 2;
            int wl = f0 / T1, t = f0 - wl * T1;
            float vv[4];
#pragma unroll
            for (int u = 0; u < 4; u++) {
                vv[u] = (float)(gbase + (int)nodes_l[wl * NSTR + t]);
                t++; if (t == T1) { t = 0; wl++; }
            }
            float4 v; v.x = vv[0]; v.y = vv[1]; v.z = vv[2]; v.w = vv[3];
            *reinterpret_cast<float4*>(dst + f0) = v;
        }
    }

    // out1: walk_edges [wl][50] = ((gbase+cur)<<4)+eidx   (5000 floats, <2^24 exact)
    {
        float* dst = out + (size_t)N * T1 + (size_t)wbase * STEPS_C;
        const int n4 = (WPB * STEPS_C) >> 2;     // 1250
        for (int c = tid; c < n4; c += BLOCK) {
            const int f0 = c << 2;
            int wl = f0 / STEPS_C, t = f0 - wl * STEPS_C;
            float vv[4];
#pragma unroll
            for (int u = 0; u < 4; u++) {
                vv[u] = (float)((((gbase + (int)nodes_l[wl * NSTR + t])) << 4)
                                + (int)eidx_l[wl * NSTR + t]);
                t++; if (t == STEPS_C) { t = 0; wl++; }
            }
            float4 v; v.x = vv[0]; v.y = vv[1]; v.z = vv[2]; v.w = vv[3];
            *reinterpret_cast<float4*>(dst + f0) = v;
        }
    }

    // out2: walk_x [wl][j<15][t<51] = bit t of mask_l[wl][j]   (76500 floats)
    {
        float* dst = out + (size_t)N * (T1 + STEPS_C) + (size_t)wbase * (FRD * T1);
        const int n4 = (WPB * FRD * T1) >> 2;    // 19125
        for (int c = tid; c < n4; c += BLOCK) {
            const int f0 = c << 2;
            int wl = f0 / (FRD * T1), rem = f0 - wl * (FRD * T1);
            int j = rem / T1, t = rem - j * T1;
            float vv[4];
#pragma unroll
            for (int u = 0; u < 4; u++) {
                vv[u] = ((mask_l[wl * MSTR + j] >> t) & 1ull) ? 1.0f : 0.0f;
                t++;
                if (t == T1) { t = 0; j++; if (j == FRD) { j = 0; wl++; } }
            }
            float4 v; v.x = vv[0]; v.y = vv[1]; v.z = vv[2]; v.w = vv[3];
            *reinterpret_cast<float4*>(dst + f0) = v;
        }
    }
}

extern "C" void kernel_launch(void* const* d_in, const int* in_sizes, int n_in,
                              void* d_out, int out_size, void* d_ws, size_t ws_size,
                              hipStream_t stream) {
    const int N = in_sizes[3];               // 50000
    const int num_graphs = N / ORDER;        // 100
    const int grid = num_graphs * BPG;       // 500 blocks, 100 walkers each

    fused_kernel<<<grid, BLOCK, 0, stream>>>(
        (const int*)d_in[0], (const int*)d_in[4], (const int*)d_in[5],
        (float*)d_out, N);
}